// Round 9
// baseline (385.617 us; speedup 1.0000x reference)
//
#include <hip/hip_runtime.h>
#include <hip/hip_bf16.h>
#include <stdint.h>

typedef float  f32x4  __attribute__((ext_vector_type(4)));
typedef float  f32x16 __attribute__((ext_vector_type(16)));
typedef unsigned int   u32x4 __attribute__((ext_vector_type(4)));
typedef unsigned short u16x4 __attribute__((ext_vector_type(4)));
typedef int    i32x4  __attribute__((ext_vector_type(4)));

__device__ inline unsigned short f2bf(float f) {
  unsigned int u = __builtin_bit_cast(unsigned int, f);
  u += 0x7fffu + ((u >> 16) & 1u);   // round-to-nearest-even
  return (unsigned short)(u >> 16);
}

__device__ inline void mfma32x32x16bf16(f32x16& acc, u32x4 a, u32x4 b) {
  asm volatile("v_mfma_f32_32x32x16_bf16 %0, %1, %2, %0"
               : "+v"(acc)
               : "v"(a), "v"(b));
}

__device__ inline void mfma16x16x32bf16(f32x4& acc, u32x4 a, u32x4 b) {
  asm volatile("v_mfma_f32_16x16x32_bf16 %0, %1, %2, %0"
               : "+v"(acc)
               : "v"(a), "v"(b));
}

// ======================================================================
// Fragment-ordered tiles for 32x32x16 MFMA (verified R3-R7).
// Tile (256 rows x 64 k) = 2048 chunks of 16B. Chunk c = s*512 + f*64 + lane
//   (s = k>>4, f = row>>5, lane = (row&31) + 32*((k>>3)&1)); 8 bf16/chunk.
// Each kh half (s pair) = contiguous 16 KB = one BK=32 subtile.
// ======================================================================

// prep_x: x fp32 [M][K] -> xb fragment-ordered bf16
__global__ __launch_bounds__(256) void prep_x(const float* __restrict__ x,
                                              unsigned short* __restrict__ xb,
                                              int K, int KT) {
  const int rb = blockIdx.x / KT;
  const int kt = blockIdx.x % KT;
  __shared__ unsigned short t[256 * 64];
  const int tid = threadIdx.x;
  const int klane = tid & 15;        // *4 floats along k
  const int rbase = tid >> 4;        // 0..15
  const float* src = x + (size_t)(rb * 256) * K + kt * 64;
  const int gw = klane >> 1, hw = klane & 1;   // 8-elem group, half
  for (int it = 0; it < 16; ++it) {
    int row = it * 16 + rbase;
    f32x4 v = *(const f32x4*)(src + (size_t)row * K + klane * 4);
    u16x4 h;
    h[0] = f2bf(v[0]); h[1] = f2bf(v[1]); h[2] = f2bf(v[2]); h[3] = f2bf(v[3]);
    *(u16x4*)&t[row * 64 + ((gw ^ (row & 7)) << 3) + hw * 4] = h;   // XOR-swizzled
  }
  __syncthreads();
  unsigned short* dst = xb + ((size_t)rb * KT + kt) * 16384;
  for (int j = 0; j < 8; ++j) {
    int c = j * 256 + tid;            // output-linear 16B chunk index
    int l = c & 63, f = (c >> 6) & 7, s = c >> 9;
    int row = f * 32 + (l & 31);
    int g   = (s * 2 + (l >> 5)) ^ (row & 7);
    u32x4 v = *(const u32x4*)&t[row * 64 + (g << 3)];
    *(u32x4*)(dst + (size_t)c * 8) = v;
  }
}

// prep_w: wq int32 [N][K], zp -> wb = bf16(w - zp) fragment-ordered
__global__ __launch_bounds__(256) void prep_w(const int* __restrict__ wq,
                                              const int* __restrict__ zp,
                                              unsigned short* __restrict__ wb,
                                              int K, int KT) {
  const int cb = blockIdx.x / KT;
  const int kt = blockIdx.x % KT;
  __shared__ unsigned short t[256 * 64];
  const int tid = threadIdx.x;
  const int klane = tid & 15;
  const int rbase = tid >> 4;
  const int* src = wq + (size_t)(cb * 256) * K + kt * 64;
  const int gw = klane >> 1, hw = klane & 1;
  for (int it = 0; it < 16; ++it) {
    int row = it * 16 + rbase;
    i32x4 v = *(const i32x4*)(src + (size_t)row * K + klane * 4);
    int z = zp[cb * 256 + row];
    u16x4 h;
    h[0] = f2bf((float)(v[0] - z)); h[1] = f2bf((float)(v[1] - z));
    h[2] = f2bf((float)(v[2] - z)); h[3] = f2bf((float)(v[3] - z));
    *(u16x4*)&t[row * 64 + ((gw ^ (row & 7)) << 3) + hw * 4] = h;
  }
  __syncthreads();
  unsigned short* dst = wb + ((size_t)cb * KT + kt) * 16384;
  for (int j = 0; j < 8; ++j) {
    int c = j * 256 + tid;
    int l = c & 63, f = (c >> 6) & 7, s = c >> 9;
    int row = f * 32 + (l & 31);
    int g   = (s * 2 + (l >> 5)) ^ (row & 7);
    u32x4 v = *(const u32x4*)&t[row * 64 + (g << 3)];
    *(u32x4*)(dst + (size_t)c * 8) = v;
  }
}

// ======================================================================
// R16: 256x256 tile, 32x32x16 MFMA, *** NO LDS, NO BARRIERS ***.
// 512 thr = 8 waves (2M x 4N), per-wave 128x64 = 4x2 frags.
//
// Evidence (R7-R15): every lockstep schedule = 253-275us, MfmaUtil
// pinned ~50%. Zero-overlap arithmetic (LDS drain 1152 + stage 250 +
// matrix 1033 + edges = 2435cyc) matches measured 2372cyc/subtile:
// barrier-released waves get round-robin LDS service, so every wave's
// operands complete at end-of-drain and the pipes fully serialize.
// The collective barrier exists only because LDS slots were staged
// cooperatively. Fragment-ordered xb/wb make every MFMA fragment a
// contiguous, coalesced 1KB global read (base + lane*16) — so skip
// LDS entirely: load fragments DIRECTLY global -> VGPR, per wave,
// double-buffered one subtile ahead (two static FragSets, ping-pong,
// fully unrolled -> no scratch). Each wave free-runs {issue 12 loads
// (u+1); MFMA(u) gated by compiler fine-grained vmcnt}; waves drift
// and fill each other's pipe gaps. L1 (32KB = one subtile working
// set) broadcasts shared chunks (A-chunk: 4 waves, B-chunk: 2 waves);
// drift is self-limiting (identical per-body work).
// Registers: acc 128 + 2x48 operand sets + addr ~= 240 < 256
// (launch_bounds 512,2).
// ======================================================================
__global__ __launch_bounds__(512, 2) void gemm_ring(
    const unsigned short* __restrict__ xb, const unsigned short* __restrict__ wb,
    const float* __restrict__ scale, const float* __restrict__ bias,
    float* __restrict__ out, int N, int KT) {   // KT = K/32 subtiles

  const int NB = N >> 8;
  // T1: XCD-aware swizzle (nwg % 8 == 0 guaranteed by launcher)
  const int nwg = gridDim.x;
  const int wg  = (blockIdx.x & 7) * (nwg >> 3) + (blockIdx.x >> 3);
  const int rb = wg / NB;
  const int cb = wg % NB;

  const int tid  = threadIdx.x;
  const int lane = tid & 63;
  const int wave = tid >> 6;
  const int wr = wave >> 2;        // 0..1  (M)
  const int wc = wave & 3;         // 0..3  (N)
  const int wr4 = wr * 4, wc2 = wc * 2;
  const int lane8 = lane * 8;      // shorts

  // subtile u of A: xtb + u*8192 shorts (16 KB); same for B
  const unsigned short* xtb = xb + (size_t)rb * (KT >> 1) * 16384;
  const unsigned short* wtb = wb + (size_t)cb * (KT >> 1) * 16384;

  f32x16 acc[4][2] = {};

  struct FragSet { u32x4 a[2][4]; u32x4 b[2][2]; };

  // 12 contiguous 1KB wave-loads per subtile; all indices compile-time
  // after unroll (rule 20: no runtime-indexed reg arrays).
  auto LOADSET = [&](FragSet& F, int u) {
    const unsigned short* xa = xtb + (size_t)u * 8192;
    const unsigned short* wa = wtb + (size_t)u * 8192;
#pragma unroll
    for (int s = 0; s < 2; ++s) {
#pragma unroll
      for (int n = 0; n < 2; ++n)
        F.b[s][n] = *(const u32x4*)(wa + s * 4096 + (wc2 + n) * 512 + lane8);
#pragma unroll
      for (int m = 0; m < 4; ++m)
        F.a[s][m] = *(const u32x4*)(xa + s * 4096 + (wr4 + m) * 512 + lane8);
    }
  };

  auto MM = [&](FragSet& F) {
    __builtin_amdgcn_s_setprio(1);
#pragma unroll
    for (int s = 0; s < 2; ++s)
#pragma unroll
      for (int m = 0; m < 4; ++m) {
        mfma32x32x16bf16(acc[m][0], F.a[s][m], F.b[s][0]);
        mfma32x32x16bf16(acc[m][1], F.a[s][m], F.b[s][1]);
      }
    __builtin_amdgcn_s_setprio(0);
  };

  FragSet fsA, fsB;              // static ping-pong (no runtime indexing)
  LOADSET(fsA, 0);

  int u = 0;
  for (; u + 2 < KT; u += 2) {   // KT even, >= 8
    LOADSET(fsB, u + 1);         // issue next-subtile loads first
    MM(fsA);                     // compute u (compiler fine-grained vmcnt)
    LOADSET(fsA, u + 2);
    MM(fsB);                     // compute u+1
  }
  LOADSET(fsB, u + 1);           // u = KT-2
  MM(fsA);
  MM(fsB);                       // u = KT-1

  // -------- epilogue: C/D layout col=lane&31, row=(reg&3)+8*(reg>>2)+4*(lane>>5)
  const int m0 = rb * 256 + wr * 128;
  const int n0 = cb * 256 + wc * 64;
  const int l31 = lane & 31, lhi = lane >> 5;
#pragma unroll
  for (int n = 0; n < 2; ++n) {
    const int col = n0 + n * 32 + l31;
    const float sc = scale[col];
    const float bi = bias[col];
#pragma unroll
    for (int m = 0; m < 4; ++m) {
      f32x16 v = acc[m][n];
      const int rowb = m0 + m * 32 + 4 * lhi;
#pragma unroll
      for (int q = 0; q < 4; ++q)
#pragma unroll
        for (int r = 0; r < 4; ++r)
          out[(size_t)(rowb + q * 8 + r) * N + col] = v[q * 4 + r] * sc + bi;
    }
  }
}

// ======================================================================
// Fallback (no workspace): 128x128 tile, in-loop dequant, 16x16x32
// ======================================================================
__global__ __launch_bounds__(256) void gemm_fallback(
    const float* __restrict__ x, const int* __restrict__ wq, const int* __restrict__ zp,
    const float* __restrict__ scale, const float* __restrict__ bias,
    float* __restrict__ out, int M, int N, int K) {

  __shared__ unsigned short Alds[128 * 32];
  __shared__ unsigned short Blds[128 * 32];

  const int tid = threadIdx.x;
  const int ntile = N / 128;
  const int m0 = (blockIdx.x / ntile) * 128, n0 = (blockIdx.x % ntile) * 128;
  const int lane = tid & 63;
  const int wave = tid >> 6;
  const int wr = wave >> 1, wc = wave & 1;
  const int lr = lane & 15, lhi = lane >> 4;
  f32x4 acc[4][4] = {};
  const int ar = tid >> 3, ac4 = tid & 7;

  for (int k0 = 0; k0 < K; k0 += 32) {
#pragma unroll
    for (int p = 0; p < 4; ++p) {
      int r = p * 32 + ar;
      i32x4 w = *(const i32x4*)(wq + (size_t)(n0 + r) * K + k0 + ac4 * 4);
      int z = zp[n0 + r];
      u16x4 h;
      h[0] = f2bf((float)(w[0] - z)); h[1] = f2bf((float)(w[1] - z));
      h[2] = f2bf((float)(w[2] - z)); h[3] = f2bf((float)(w[3] - z));
      *(u16x4*)&Blds[r * 32 + ac4 * 4] = h;
    }
#pragma unroll
    for (int p = 0; p < 4; ++p) {
      int r = p * 32 + ar;
      f32x4 v = *(const f32x4*)(x + (size_t)(m0 + r) * K + k0 + ac4 * 4);
      u16x4 h;
      h[0] = f2bf(v[0]); h[1] = f2bf(v[1]); h[2] = f2bf(v[2]); h[3] = f2bf(v[3]);
      *(u16x4*)&Alds[r * 32 + ac4 * 4] = h;
    }
    __syncthreads();
    u32x4 af[4], bf[4];
#pragma unroll
    for (int i = 0; i < 4; ++i) {
      af[i] = *(const u32x4*)&Alds[(wr * 64 + i * 16 + lr) * 32 + lhi * 8];
      bf[i] = *(const u32x4*)&Blds[(wc * 64 + i * 16 + lr) * 32 + lhi * 8];
    }
#pragma unroll
    for (int i = 0; i < 4; ++i)
#pragma unroll
      for (int j = 0; j < 4; ++j)
        mfma16x16x32bf16(acc[i][j], af[i], bf[j]);
    __syncthreads();
  }
  const int crow0 = m0 + wr * 64;
  const int ccol0 = n0 + wc * 64 + lr;
#pragma unroll
  for (int j = 0; j < 4; ++j) {
    int col = ccol0 + j * 16;
    float sc = scale[col], bi = bias[col];
#pragma unroll
    for (int i = 0; i < 4; ++i) {
      int row = crow0 + i * 16 + lhi * 4;
      f32x4 v = acc[i][j];
#pragma unroll
      for (int r = 0; r < 4; ++r)
        out[(size_t)(row + r) * N + col] = v[r] * sc + bi;
    }
  }
}

extern "C" void kernel_launch(void* const* d_in, const int* in_sizes, int n_in,
                              void* d_out, int out_size, void* d_ws, size_t ws_size,
                              hipStream_t stream) {
  const float* x     = (const float*)d_in[0];
  const int*   wq    = (const int*)d_in[1];
  const float* scale = (const float*)d_in[2];
  const int*   zp    = (const int*)d_in[3];
  const float* bias  = (const float*)d_in[4];
  float* out = (float*)d_out;

  const int DOUT = in_sizes[4];             // 4096
  const int DIN  = in_sizes[1] / DOUT;      // 4096
  const int M    = in_sizes[0] / DIN;       // 8192

  const size_t needX = (size_t)M * DIN * 2;
  const size_t needW = (size_t)DOUT * DIN * 2;

  const int nwg  = (M / 256) * (DOUT / 256);
  const int KT64 = DIN / 64;
  const int KT32 = DIN / 32;
  const bool shapes_ok = (M % 256 == 0) && (DOUT % 256 == 0) && (DIN % 64 == 0) &&
                         (nwg % 8 == 0) && (KT32 >= 8) && (KT32 % 2 == 0);

  if (shapes_ok && ws_size >= needX + needW) {
    unsigned short* xb = (unsigned short*)d_ws;
    unsigned short* wb = (unsigned short*)((char*)d_ws + needX);
    prep_x<<<(M / 256) * KT64, 256, 0, stream>>>(x, xb, DIN, KT64);
    prep_w<<<(DOUT / 256) * KT64, 256, 0, stream>>>(wq, zp, wb, DIN, KT64);
    gemm_ring<<<nwg, 512, 0, stream>>>(xb, wb, scale, bias, out, DOUT, KT32);
  } else {
    dim3 grid((M / 128) * (DOUT / 128));
    gemm_fallback<<<grid, 256, 0, stream>>>(x, wq, zp, scale, bias, out, M, DOUT, DIN);
  }
}

// Round 10
// 299.104 us; speedup vs baseline: 1.2892x; 1.2892x over previous
//
#include <hip/hip_runtime.h>
#include <hip/hip_bf16.h>
#include <stdint.h>

typedef float  f32x4  __attribute__((ext_vector_type(4)));
typedef float  f32x16 __attribute__((ext_vector_type(16)));
typedef unsigned int   u32x4 __attribute__((ext_vector_type(4)));
typedef unsigned short u16x4 __attribute__((ext_vector_type(4)));
typedef int    i32x4  __attribute__((ext_vector_type(4)));

__device__ inline unsigned short f2bf(float f) {
  unsigned int u = __builtin_bit_cast(unsigned int, f);
  u += 0x7fffu + ((u >> 16) & 1u);   // round-to-nearest-even
  return (unsigned short)(u >> 16);
}

__device__ inline void mfma32x32x16bf16(f32x16& acc, u32x4 a, u32x4 b) {
  asm volatile("v_mfma_f32_32x32x16_bf16 %0, %1, %2, %0"
               : "+v"(acc)
               : "v"(a), "v"(b));
}

__device__ inline void mfma16x16x32bf16(f32x4& acc, u32x4 a, u32x4 b) {
  asm volatile("v_mfma_f32_16x16x32_bf16 %0, %1, %2, %0"
               : "+v"(acc)
               : "v"(a), "v"(b));
}

__device__ inline void gload16(const unsigned short* src, char* ldsdst) {
  __builtin_amdgcn_global_load_lds(
      (const __attribute__((address_space(1))) void*)src,
      (__attribute__((address_space(3))) void*)ldsdst, 16, 0, 0);
}

// ======================================================================
// Fragment-ordered tiles for 32x32x16 MFMA (verified R3-R7).
// Tile (256 rows x 64 k) = 2048 chunks of 16B. Chunk c = s*512 + f*64 + lane
//   (s = k>>4, f = row>>5, lane = (row&31) + 32*((k>>3)&1)); 8 bf16/chunk.
// Each kh half (s pair) = contiguous 16 KB = one BK=32 subtile.
// ======================================================================

// prep_x: x fp32 [M][K] -> xb fragment-ordered bf16
__global__ __launch_bounds__(256) void prep_x(const float* __restrict__ x,
                                              unsigned short* __restrict__ xb,
                                              int K, int KT) {
  const int rb = blockIdx.x / KT;
  const int kt = blockIdx.x % KT;
  __shared__ unsigned short t[256 * 64];
  const int tid = threadIdx.x;
  const int klane = tid & 15;        // *4 floats along k
  const int rbase = tid >> 4;        // 0..15
  const float* src = x + (size_t)(rb * 256) * K + kt * 64;
  const int gw = klane >> 1, hw = klane & 1;   // 8-elem group, half
  for (int it = 0; it < 16; ++it) {
    int row = it * 16 + rbase;
    f32x4 v = *(const f32x4*)(src + (size_t)row * K + klane * 4);
    u16x4 h;
    h[0] = f2bf(v[0]); h[1] = f2bf(v[1]); h[2] = f2bf(v[2]); h[3] = f2bf(v[3]);
    *(u16x4*)&t[row * 64 + ((gw ^ (row & 7)) << 3) + hw * 4] = h;   // XOR-swizzled
  }
  __syncthreads();
  unsigned short* dst = xb + ((size_t)rb * KT + kt) * 16384;
  for (int j = 0; j < 8; ++j) {
    int c = j * 256 + tid;            // output-linear 16B chunk index
    int l = c & 63, f = (c >> 6) & 7, s = c >> 9;
    int row = f * 32 + (l & 31);
    int g   = (s * 2 + (l >> 5)) ^ (row & 7);
    u32x4 v = *(const u32x4*)&t[row * 64 + (g << 3)];
    *(u32x4*)(dst + (size_t)c * 8) = v;
  }
}

// prep_w: wq int32 [N][K], zp -> wb = bf16(w - zp) fragment-ordered
__global__ __launch_bounds__(256) void prep_w(const int* __restrict__ wq,
                                              const int* __restrict__ zp,
                                              unsigned short* __restrict__ wb,
                                              int K, int KT) {
  const int cb = blockIdx.x / KT;
  const int kt = blockIdx.x % KT;
  __shared__ unsigned short t[256 * 64];
  const int tid = threadIdx.x;
  const int klane = tid & 15;
  const int rbase = tid >> 4;
  const int* src = wq + (size_t)(cb * 256) * K + kt * 64;
  const int gw = klane >> 1, hw = klane & 1;
  for (int it = 0; it < 16; ++it) {
    int row = it * 16 + rbase;
    i32x4 v = *(const i32x4*)(src + (size_t)row * K + klane * 4);
    int z = zp[cb * 256 + row];
    u16x4 h;
    h[0] = f2bf((float)(v[0] - z)); h[1] = f2bf((float)(v[1] - z));
    h[2] = f2bf((float)(v[2] - z)); h[3] = f2bf((float)(v[3] - z));
    *(u16x4*)&t[row * 64 + ((gw ^ (row & 7)) << 3) + hw * 4] = h;
  }
  __syncthreads();
  unsigned short* dst = wb + ((size_t)cb * KT + kt) * 16384;
  for (int j = 0; j < 8; ++j) {
    int c = j * 256 + tid;
    int l = c & 63, f = (c >> 6) & 7, s = c >> 9;
    int row = f * 32 + (l & 31);
    int g   = (s * 2 + (l >> 5)) ^ (row & 7);
    u32x4 v = *(const u32x4*)&t[row * 64 + (g << 3)];
    *(u32x4*)(dst + (size_t)c * 8) = v;
  }
}

// ======================================================================
// 256x256 GEMM, 32x32x16 MFMA, 4-slot LDS ring, BK=32 subtiles.
// 512 thr = 8 waves (2M x 4N), per-wave 128x64 = 4x2 frags.
//
// R17: FAITHFUL m201 8-phase schedule. One phase per k-slice (2/subtile):
//   { 6 ds_reads (slice s) ; 2 gload_lds drip } -> BAR ->
//   lgkmcnt(0) -> sched_barrier(0) -> setprio(1) -> 8 MFMA -> setprio(0)
//   -> [phase B only: counted vmcnt] -> BAR
// Matches m201's granularity per phase (48KB CU-wide ds_reads, ~520-620
// cyc MFMA window) and its barrier count (4/subtile == 16/iteration).
// Reads are issued BEFORE the mid-phase barrier (their drain overlaps
// the barrier convergence + other waves' MFMA windows); the pure-MFMA
// cluster runs uninterrupted after lgkmcnt(0).
//
// RAW: slot u collectively ready at subtile u-1's closing barrier
// (counted vmcnt placed before it — R15-verified invariant); phase-A(u)
// reads follow that barrier. WAR: STAGE(u+3) (slot (u-1)&3) issued
// after that same barrier; every wave's slot-(u-1) reads were
// lgkm(0)-drained before its phase-B(u-1) MFMAs.
// vmcnt ledger (4 gloads/subtile, dripped 2 in phase A + 2 in phase B):
// at phase-B(u) vmcnt: queue = {stage(u+1),(u+2),(u+3)} = 12 ->
// vmcnt(8) drains stage(u+1). Tails: KT-3 -> 4, KT-2 -> 0, KT-1 -> 0.
// ======================================================================
__global__ __launch_bounds__(512, 2) void gemm_ring(
    const unsigned short* __restrict__ xb, const unsigned short* __restrict__ wb,
    const float* __restrict__ scale, const float* __restrict__ bias,
    float* __restrict__ out, int N, int KT) {   // KT = K/32 subtiles

  __shared__ unsigned short lds[65536];   // 128 KiB = 4 slots x 32 KB

  const int NB = N >> 8;
  // T1: XCD-aware swizzle (nwg % 8 == 0 guaranteed by launcher)
  const int nwg = gridDim.x;
  const int wg  = (blockIdx.x & 7) * (nwg >> 3) + (blockIdx.x >> 3);
  const int rb = wg / NB;
  const int cb = wg % NB;

  const int tid  = threadIdx.x;
  const int lane = tid & 63;
  const int wave = tid >> 6;
  const int wr = wave >> 2;        // 0..1  (M)
  const int wc = wave & 3;         // 0..3  (N)
  const int wr4 = wr * 4, wc2 = wc * 2;
  const int lane16 = lane * 16;

  // subtile u of A: xtb + u*8192 shorts (16 KB); same for B
  const unsigned short* xtb = xb + (size_t)rb * (KT >> 1) * 16384;
  const unsigned short* wtb = wb + (size_t)cb * (KT >> 1) * 16384;

  f32x16 acc[4][2] = {};

  auto STAGE_A = [&](int u) {      // 2 gloads: A-matrix half of slot
    const int slot = (u & 3) << 15;
    const unsigned short* as = xtb + (size_t)u * 8192;
    char* da = (char*)lds + slot + wave * 2048;           // wave-uniform
    gload16(as + wave * 1024 + lane * 8, da);
    gload16(as + wave * 1024 + 512 + lane * 8, da + 1024);
  };
  auto STAGE_B = [&](int u) {      // 2 gloads: B-matrix half of slot
    const int slot = (u & 3) << 15;
    const unsigned short* bs = wtb + (size_t)u * 8192;
    char* db = (char*)lds + slot + 16384 + wave * 2048;
    gload16(bs + wave * 1024 + lane * 8, db);
    gload16(bs + wave * 1024 + 512 + lane * 8, db + 1024);
  };

  auto LDA = [&](int slotb, int s, int m) -> u32x4 {
    return *(const u32x4*)((const char*)lds + slotb + s * 8192 +
                           (wr4 + m) * 1024 + lane16);
  };
  auto LDB = [&](int slotb, int s, int n) -> u32x4 {
    return *(const u32x4*)((const char*)lds + slotb + 16384 + s * 8192 +
                           (wc2 + n) * 1024 + lane16);
  };

  // ---- one phase: k-slice S of subtile U. DRIP: staging lambda or nop.
#define PHASE(U, S, DRIP, VMASM)                                               \
  {                                                                            \
    const int sb = ((U) & 3) << 15;                                            \
    u32x4 b0 = LDB(sb, S, 0), b1 = LDB(sb, S, 1);                              \
    u32x4 a0 = LDA(sb, S, 0), a1 = LDA(sb, S, 1);                              \
    u32x4 a2 = LDA(sb, S, 2), a3 = LDA(sb, S, 3);                              \
    DRIP;                                                                      \
    __builtin_amdgcn_s_barrier();                                              \
    asm volatile("s_waitcnt lgkmcnt(0)" ::: "memory");                         \
    __builtin_amdgcn_sched_barrier(0);                                         \
    __builtin_amdgcn_s_setprio(1);                                             \
    mfma32x32x16bf16(acc[0][0], a0, b0);                                       \
    mfma32x32x16bf16(acc[0][1], a0, b1);                                       \
    mfma32x32x16bf16(acc[1][0], a1, b0);                                       \
    mfma32x32x16bf16(acc[1][1], a1, b1);                                       \
    mfma32x32x16bf16(acc[2][0], a2, b0);                                       \
    mfma32x32x16bf16(acc[2][1], a2, b1);                                       \
    mfma32x32x16bf16(acc[3][0], a3, b0);                                       \
    mfma32x32x16bf16(acc[3][1], a3, b1);                                       \
    __builtin_amdgcn_s_setprio(0);                                             \
    VMASM;                                                                     \
    __builtin_amdgcn_s_barrier();                                              \
  }

#define VM8 asm volatile("s_waitcnt vmcnt(8)" ::: "memory")
#define VM4 asm volatile("s_waitcnt vmcnt(4)" ::: "memory")
#define VM0 asm volatile("s_waitcnt vmcnt(0)" ::: "memory")

  // -------- prologue: fill depth-3; make slot 0 collectively ready --------
  STAGE_A(0); STAGE_B(0); STAGE_A(1); STAGE_B(1); STAGE_A(2); STAGE_B(2);
  asm volatile("s_waitcnt vmcnt(8)" ::: "memory");   // drain own stage(0)
  __builtin_amdgcn_s_barrier();                      // collective: slot 0 ready

  int u = 0;
  for (; u + 3 < KT; ++u) {
    PHASE(u, 0, STAGE_A(u + 3), );        // phase A: drip A-half
    PHASE(u, 1, STAGE_B(u + 3), VM8);     // phase B: drip B-half + counted vmcnt
  }
  PHASE(u, 0, , );  PHASE(u, 1, , VM4); ++u;   // u = KT-3
  PHASE(u, 0, , );  PHASE(u, 1, , VM0); ++u;   // u = KT-2
  PHASE(u, 0, , );  PHASE(u, 1, , );           // u = KT-1
#undef PHASE
#undef VM8
#undef VM4
#undef VM0

  // -------- epilogue: C/D layout col=lane&31, row=(reg&3)+8*(reg>>2)+4*(lane>>5)
  const int m0 = rb * 256 + wr * 128;
  const int n0 = cb * 256 + wc * 64;
  const int l31 = lane & 31, lhi = lane >> 5;
#pragma unroll
  for (int n = 0; n < 2; ++n) {
    const int col = n0 + n * 32 + l31;
    const float sc = scale[col];
    const float bi = bias[col];
#pragma unroll
    for (int m = 0; m < 4; ++m) {
      f32x16 v = acc[m][n];
      const int rowb = m0 + m * 32 + 4 * lhi;
#pragma unroll
      for (int q = 0; q < 4; ++q)
#pragma unroll
        for (int r = 0; r < 4; ++r)
          out[(size_t)(rowb + q * 8 + r) * N + col] = v[q * 4 + r] * sc + bi;
    }
  }
}

// ======================================================================
// Fallback (no workspace): 128x128 tile, in-loop dequant, 16x16x32
// ======================================================================
__global__ __launch_bounds__(256) void gemm_fallback(
    const float* __restrict__ x, const int* __restrict__ wq, const int* __restrict__ zp,
    const float* __restrict__ scale, const float* __restrict__ bias,
    float* __restrict__ out, int M, int N, int K) {

  __shared__ unsigned short Alds[128 * 32];
  __shared__ unsigned short Blds[128 * 32];

  const int tid = threadIdx.x;
  const int ntile = N / 128;
  const int m0 = (blockIdx.x / ntile) * 128, n0 = (blockIdx.x % ntile) * 128;
  const int lane = tid & 63;
  const int wave = tid >> 6;
  const int wr = wave >> 1, wc = wave & 1;
  const int lr = lane & 15, lhi = lane >> 4;
  f32x4 acc[4][4] = {};
  const int ar = tid >> 3, ac4 = tid & 7;

  for (int k0 = 0; k0 < K; k0 += 32) {
#pragma unroll
    for (int p = 0; p < 4; ++p) {
      int r = p * 32 + ar;
      i32x4 w = *(const i32x4*)(wq + (size_t)(n0 + r) * K + k0 + ac4 * 4);
      int z = zp[n0 + r];
      u16x4 h;
      h[0] = f2bf((float)(w[0] - z)); h[1] = f2bf((float)(w[1] - z));
      h[2] = f2bf((float)(w[2] - z)); h[3] = f2bf((float)(w[3] - z));
      *(u16x4*)&Blds[r * 32 + ac4 * 4] = h;
    }
#pragma unroll
    for (int p = 0; p < 4; ++p) {
      int r = p * 32 + ar;
      f32x4 v = *(const f32x4*)(x + (size_t)(m0 + r) * K + k0 + ac4 * 4);
      u16x4 h;
      h[0] = f2bf(v[0]); h[1] = f2bf(v[1]); h[2] = f2bf(v[2]); h[3] = f2bf(v[3]);
      *(u16x4*)&Alds[r * 32 + ac4 * 4] = h;
    }
    __syncthreads();
    u32x4 af[4], bf[4];
#pragma unroll
    for (int i = 0; i < 4; ++i) {
      af[i] = *(const u32x4*)&Alds[(wr * 64 + i * 16 + lr) * 32 + lhi * 8];
      bf[i] = *(const u32x4*)&Blds[(wc * 64 + i * 16 + lr) * 32 + lhi * 8];
    }
#pragma unroll
    for (int i = 0; i < 4; ++i)
#pragma unroll
      for (int j = 0; j < 4; ++j)
        mfma16x16x32bf16(acc[i][j], af[i], bf[j]);
    __syncthreads();
  }
  const int crow0 = m0 + wr * 64;
  const int ccol0 = n0 + wc * 64 + lr;
#pragma unroll
  for (int j = 0; j < 4; ++j) {
    int col = ccol0 + j * 16;
    float sc = scale[col], bi = bias[col];
#pragma unroll
    for (int i = 0; i < 4; ++i) {
      int row = crow0 + i * 16 + lhi * 4;
      f32x4 v = acc[i][j];
#pragma unroll
      for (int r = 0; r < 4; ++r)
        out[(size_t)(row + r) * N + col] = v[r] * sc + bi;
    }
  }
}

extern "C" void kernel_launch(void* const* d_in, const int* in_sizes, int n_in,
                              void* d_out, int out_size, void* d_ws, size_t ws_size,
                              hipStream_t stream) {
  const float* x     = (const float*)d_in[0];
  const int*   wq    = (const int*)d_in[1];
  const float* scale = (const float*)d_in[2];
  const int*   zp    = (const int*)d_in[3];
  const float* bias  = (const float*)d_in[4];
  float* out = (float*)d_out;

  const int DOUT = in_sizes[4];             // 4096
  const int DIN  = in_sizes[1] / DOUT;      // 4096
  const int M    = in_sizes[0] / DIN;       // 8192

  const size_t needX = (size_t)M * DIN * 2;
  const size_t needW = (size_t)DOUT * DIN * 2;

  const int nwg  = (M / 256) * (DOUT / 256);
  const int KT64 = DIN / 64;
  const int KT32 = DIN / 32;
  const bool shapes_ok = (M % 256 == 0) && (DOUT % 256 == 0) && (DIN % 64 == 0) &&
                         (nwg % 8 == 0) && (KT32 >= 8);

  if (shapes_ok && ws_size >= needX + needW) {
    unsigned short* xb = (unsigned short*)d_ws;
    unsigned short* wb = (unsigned short*)((char*)d_ws + needX);
    prep_x<<<(M / 256) * KT64, 256, 0, stream>>>(x, xb, DIN, KT64);
    prep_w<<<(DOUT / 256) * KT64, 256, 0, stream>>>(wq, zp, wb, DIN, KT64);
    gemm_ring<<<nwg, 512, 0, stream>>>(xb, wb, scale, bias, out, DOUT, KT32);
  } else {
    dim3 grid((M / 128) * (DOUT / 128));
    gemm_fallback<<<grid, 256, 0, stream>>>(x, wq, zp, scale, bias, out, M, DOUT, DIN);
  }
}